// Round 6
// baseline (322.268 us; speedup 1.0000x reference)
//
#include <hip/hip_runtime.h>
#include <math.h>

// Performer FAVOR+ fast attention — round 6.
// B=4 H=16 N=4096 D=64 M=266.
// vs round 5: (1) k_pass h-pair XCD co-location (h = high blockIdx bit) so
// k/v chunk is read once per XCD-resident pair (L2 hit for the second);
// (2) q_pass processes 2 row-groups per block (staging amortized 2x);
// (3) proj pre-converted to f16 (DNORM folded) once in reduce_ctx.

#define BH 64
#define NTOK 4096
#define DIM 64
#define MF 266
#define MPAD 272
#define NCH 4
#define CHROWS 1024
#define SUBS 16
#define RATIO 0.06131393394849658f   // 266^-0.5
#define DNORM 0.35355339059327373f   // 64^-0.25
#define DIAGC 0.0625f                // 0.5 * 64^-0.5
#define KEPS 1e-4f

#define PSTR 72     // LDS row stride in shorts (144 B)
#define QSTR 296    // q_pass ctx stride in shorts (592 B)

typedef _Float16 half8 __attribute__((ext_vector_type(8)));
typedef _Float16 half4 __attribute__((ext_vector_type(4)));
typedef __fp16 fp16x2 __attribute__((ext_vector_type(2)));   // cvt_pkrtz native type
typedef float floatx4 __attribute__((ext_vector_type(4)));
typedef short short8 __attribute__((ext_vector_type(8)));
typedef short short4s __attribute__((ext_vector_type(4)));

__device__ __forceinline__ short f2h_bits(float f) {
    union { _Float16 h; short s; } u; u.h = (_Float16)f; return u.s;
}
__device__ __forceinline__ float h2f(short s) {
    union { short s; _Float16 h; } u; u.s = s; return (float)u.h;
}
__device__ __forceinline__ unsigned cvt_pk_bf16(float lo, float hi) {
    unsigned r;
    asm("v_cvt_pk_bf16_f32 %0, %1, %2" : "=v"(r) : "v"(lo), "v"(hi));
    return r;
}
__device__ __forceinline__ unsigned encf(float f) {
    unsigned u = __float_as_uint(f);
    return (u & 0x80000000u) ? ~u : (u | 0x80000000u);
}
__device__ __forceinline__ float decf(unsigned u) {
    u = (u & 0x80000000u) ? (u & 0x7FFFFFFFu) : ~u;
    return __uint_as_float(u);
}

// ---------------------------------------------------------------- k_pass ----
__global__ __launch_bounds__(512, 4)
void k_pass(const float* __restrict__ kin, const float* __restrict__ vin,
            const float* __restrict__ proj, float* __restrict__ A0p,
            float* __restrict__ S0p, unsigned int* __restrict__ gmax)
{
    __shared__ __align__(16) short kL[2][64 * PSTR];    // k f16 [n][d]
    __shared__ __align__(16) short vT[2][64 * PSTR];    // v bf16 [e][n]
    __shared__ float diagL[2][64];
    __shared__ __align__(16) short epS[16][16 * PSTR];  // per (wave,it): ep bf16 [f][n]

    const int tid = threadIdx.x;
    const int l = tid & 63, w = tid >> 6;
    const int c = tid & 15, g = (tid >> 4) & 3;
    // h from the HIGH bit: blocks rest and rest+256 share a k/v chunk and map
    // to the same XCD (256 % 8 == 0) -> second reader hits L2.
    const int h    = blockIdx.x >> 8;
    const int rest = blockIdx.x & 255;
    const int bh   = rest >> 2;
    const int ch   = rest & 3;
    const int nT = (h == 1 && w == 0) ? 2 : 1;
    const int t0 = (h == 0) ? w : (8 + w);              // second tile (it=1) is 16

    // ---- proj B-frags in registers (only this wave's tiles)
    half8 pj0[2], pj1[2];
    #pragma unroll
    for (int it = 0; it < 2; ++it) {
        half8 z;
        #pragma unroll
        for (int j = 0; j < 8; ++j) z[j] = (_Float16)0.f;
        pj0[it] = z; pj1[it] = z;
        const int t = it ? 16 : t0;
        const int f = 16 * t + c;
        if (it < nT && f < MF) {
            const float* ps = proj + (size_t)f * 64 + 8 * g;
            float4 x0 = *(const float4*)ps;
            float4 x1 = *(const float4*)(ps + 4);
            float4 x2 = *(const float4*)(ps + 32);
            float4 x3 = *(const float4*)(ps + 36);
            half8 b0, b1;
            b0[0]=(_Float16)(DNORM*x0.x); b0[1]=(_Float16)(DNORM*x0.y);
            b0[2]=(_Float16)(DNORM*x0.z); b0[3]=(_Float16)(DNORM*x0.w);
            b0[4]=(_Float16)(DNORM*x1.x); b0[5]=(_Float16)(DNORM*x1.y);
            b0[6]=(_Float16)(DNORM*x1.z); b0[7]=(_Float16)(DNORM*x1.w);
            b1[0]=(_Float16)(DNORM*x2.x); b1[1]=(_Float16)(DNORM*x2.y);
            b1[2]=(_Float16)(DNORM*x2.z); b1[3]=(_Float16)(DNORM*x2.w);
            b1[4]=(_Float16)(DNORM*x3.x); b1[5]=(_Float16)(DNORM*x3.y);
            b1[6]=(_Float16)(DNORM*x3.z); b1[7]=(_Float16)(DNORM*x3.w);
            pj0[it] = b0; pj1[it] = b1;
        }
    }

    const float* kb = kin + ((size_t)bh * NTOK + (size_t)ch * CHROWS) * DIM;
    const float* vb = vin + ((size_t)bh * NTOK + (size_t)ch * CHROWS) * DIM;

    // staging assignments
    const int srow = 8 * w + (l >> 3);     // k: row, d-segment (l&7)*8
    const int sd0  = (l & 7) * 8;
    const int vrow = l;                    // v: row = lane, e-segment 8w..8w+7
    const int ve0  = 8 * w;

    floatx4 acc[2][4];
    #pragma unroll
    for (int it = 0; it < 2; ++it)
        #pragma unroll
        for (int et = 0; et < 4; ++et) {
            acc[it][et][0]=0.f; acc[it][et][1]=0.f; acc[it][et][2]=0.f; acc[it][et][3]=0.f;
        }
    float s0acc[2] = {0.f, 0.f};
    float dmax = -3.0e38f;

    float4 ka0, ka1, va0, va1;

    auto issue_loads = [&](int s) {
        const float* ks = kb + (size_t)(64 * s + srow) * DIM + sd0;
        ka0 = *(const float4*)ks;
        ka1 = *(const float4*)(ks + 4);
        const float* vs = vb + (size_t)(64 * s + vrow) * DIM + ve0;
        va0 = *(const float4*)vs;
        va1 = *(const float4*)(vs + 4);
    };

    auto stage_write = [&](int buf) {
        // k -> f16 row-major
        union { fp16x2 h2[4]; short8 s8; } uk;
        uk.h2[0] = __builtin_amdgcn_cvt_pkrtz(ka0.x, ka0.y);
        uk.h2[1] = __builtin_amdgcn_cvt_pkrtz(ka0.z, ka0.w);
        uk.h2[2] = __builtin_amdgcn_cvt_pkrtz(ka1.x, ka1.y);
        uk.h2[3] = __builtin_amdgcn_cvt_pkrtz(ka1.z, ka1.w);
        *(short8*)&kL[buf][srow * PSTR + sd0] = uk.s8;
        // diag partial + 8-lane reduce
        float ds2 = ka0.x*ka0.x + ka0.y*ka0.y + ka0.z*ka0.z + ka0.w*ka0.w
                  + ka1.x*ka1.x + ka1.y*ka1.y + ka1.z*ka1.z + ka1.w*ka1.w;
        ds2 += __shfl_xor(ds2, 1);
        ds2 += __shfl_xor(ds2, 2);
        ds2 += __shfl_xor(ds2, 4);
        if ((l & 7) == 0) diagL[buf][srow] = ds2 * DIAGC;
        // v -> bf16 transposed [e][n]
        unsigned pv0 = cvt_pk_bf16(va0.x, va0.y);
        unsigned pv1 = cvt_pk_bf16(va0.z, va0.w);
        unsigned pv2 = cvt_pk_bf16(va1.x, va1.y);
        unsigned pv3 = cvt_pk_bf16(va1.z, va1.w);
        vT[buf][(ve0 + 0) * PSTR + vrow] = (short)(pv0 & 0xFFFF);
        vT[buf][(ve0 + 1) * PSTR + vrow] = (short)(pv0 >> 16);
        vT[buf][(ve0 + 2) * PSTR + vrow] = (short)(pv1 & 0xFFFF);
        vT[buf][(ve0 + 3) * PSTR + vrow] = (short)(pv1 >> 16);
        vT[buf][(ve0 + 4) * PSTR + vrow] = (short)(pv2 & 0xFFFF);
        vT[buf][(ve0 + 5) * PSTR + vrow] = (short)(pv2 >> 16);
        vT[buf][(ve0 + 6) * PSTR + vrow] = (short)(pv3 & 0xFFFF);
        vT[buf][(ve0 + 7) * PSTR + vrow] = (short)(pv3 >> 16);
    };

    // prologue: stage sub 0
    issue_loads(0);
    stage_write(0);
    __syncthreads();

    for (int s = 0; s < SUBS; ++s) {
        const int cur = s & 1;
        const bool more = (s + 1 < SUBS);
        if (more) issue_loads(s + 1);   // HBM latency hides under compute below

        // ---- GEMM1: dd = k @ (DNORM proj)^T ; epilogue -> epS (wave-private)
        #pragma unroll
        for (int nt = 0; nt < 4; ++nt) {
            const half8 a0 = *(const half8*)&kL[cur][(16 * nt + c) * PSTR + 8 * g];
            const half8 a1 = *(const half8*)&kL[cur][(16 * nt + c) * PSTR + 8 * g + 32];
            const float4 dg4 = *(const float4*)&diagL[cur][16 * nt + 4 * g];
            const float dgr[4] = {dg4.x, dg4.y, dg4.z, dg4.w};
            #pragma unroll
            for (int it = 0; it < 2; ++it) {
                if (it < nT) {
                    floatx4 d = {0.f, 0.f, 0.f, 0.f};
                    d = __builtin_amdgcn_mfma_f32_16x16x32_f16(a0, pj0[it], d, 0, 0, 0);
                    d = __builtin_amdgcn_mfma_f32_16x16x32_f16(a1, pj1[it], d, 0, 0, 0);
                    const bool t16 = (it == 1);
                    float ev[4];
                    #pragma unroll
                    for (int r = 0; r < 4; ++r) {
                        const float ddv = d[r];
                        if (!t16 || c < 10) dmax = fmaxf(dmax, ddv);
                        float e = __expf(ddv - dgr[r]);
                        if (t16 && c == 15) e = 1.0f;   // "ones" feature -> Vs in A0 row 271
                        s0acc[it] += e;
                        ev[r] = e;
                    }
                    uint2 pk;
                    pk.x = cvt_pk_bf16(ev[0], ev[1]);
                    pk.y = cvt_pk_bf16(ev[2], ev[3]);
                    *(uint2*)&epS[2 * w + it][c * PSTR + 16 * nt + 4 * g] = pk;
                }
            }
        }

        // ---- GEMM2: A0[e][f] += v^T @ ep   (contract n, bf16 16x16x32)
        #pragma unroll
        for (int ntp = 0; ntp < 2; ++ntp) {
            const short8 bq0 = *(const short8*)&epS[2 * w][c * PSTR + 32 * ntp + 8 * g];
            short8 bq1;
            if (nT == 2) bq1 = *(const short8*)&epS[2 * w + 1][c * PSTR + 32 * ntp + 8 * g];
            #pragma unroll
            for (int et = 0; et < 4; ++et) {
                const short8 av = *(const short8*)&vT[cur][(16 * et + c) * PSTR + 32 * ntp + 8 * g];
                acc[0][et] = __builtin_amdgcn_mfma_f32_16x16x32_bf16(av, bq0, acc[0][et], 0, 0, 0);
                if (nT == 2)
                    acc[1][et] = __builtin_amdgcn_mfma_f32_16x16x32_bf16(av, bq1, acc[1][et], 0, 0, 0);
            }
        }

        if (more) {
            stage_write(cur ^ 1);
            __syncthreads();
        }
    }

    // ---- epilogue: A0 partials [m][e] (lane holds e=16et+4g..+3 contiguous)
    {
        float* dst = A0p + (size_t)(bh * NCH + ch) * (MPAD * 64);
        #pragma unroll
        for (int it = 0; it < 2; ++it) {
            if (it < nT) {
                const int t = it ? 16 : t0;
                #pragma unroll
                for (int et = 0; et < 4; ++et)
                    *(floatx4*)&dst[(size_t)(16 * t + c) * 64 + 16 * et + 4 * g] = acc[it][et];
            }
        }
    }
    // ---- S0 atomics
    #pragma unroll
    for (int it = 0; it < 2; ++it) {
        if (it < nT) {
            const int t = it ? 16 : t0;
            float s = s0acc[it];
            s += __shfl_xor(s, 16);
            s += __shfl_xor(s, 32);
            if (g == 0 && (t < 16 || c < 10))
                atomicAdd(&S0p[bh * MPAD + 16 * t + c], s);
        }
    }
    // ---- dmax
    #pragma unroll
    for (int sft = 1; sft <= 32; sft <<= 1) dmax = fmaxf(dmax, __shfl_xor(dmax, sft));
    if (l == 0) atomicMax(gmax + bh, encf(dmax));
}

// ------------------------------------------------------------ reduce_ctx ----
// ctxT_ws[bh][e'][m] f16, e'=0..63 context cols, e'=64 k_cumsum; m padded to 288.
// Blocks 0..16 also convert proj -> projw f16 (DNORM folded, rows >= 266 zero).
__global__ __launch_bounds__(512, 1)
void reduce_ctx(const float* __restrict__ A0p, const float* __restrict__ S0p,
                const unsigned int* __restrict__ gmax, const float* __restrict__ proj,
                short* __restrict__ ctxw, short* __restrict__ projw)
{
    __shared__ __align__(16) short L[65 * 288];
    const int bh = blockIdx.x, tid = threadIdx.x;
    if (bh < 17) {   // proj f16 conversion: rows 16*bh .. 16*bh+15
        #pragma unroll
        for (int rep = 0; rep < 2; ++rep) {
            const int idx = rep * 512 + tid;
            const int f = 16 * bh + (idx >> 6);
            const int d = idx & 63;
            const float val = (f < MF) ? proj[(size_t)f * 64 + d] * DNORM : 0.f;
            projw[(size_t)f * 64 + d] = f2h_bits(val);
        }
    }
    const float emx = __expf(-decf(gmax[bh]));
    const int e = tid & 63, mi = tid >> 6;
    const float* base = A0p + (size_t)bh * NCH * MPAD * 64;
    float vs = 0.f;
    #pragma unroll
    for (int c2 = 0; c2 < NCH; ++c2)
        vs += base[(size_t)c2 * MPAD * 64 + (size_t)271 * 64 + e];   // "ones" row = Vs
    const float vsr = vs * KEPS;
    for (int m = mi; m < 288; m += 8) {
        float val = 0.f;
        if (m < MF) {
            float s = 0.f;
            #pragma unroll
            for (int c2 = 0; c2 < NCH; ++c2)
                s += base[(size_t)c2 * MPAD * 64 + (size_t)m * 64 + e];
            val = RATIO * (emx * s + vsr);
        }
        L[e * 288 + m] = f2h_bits(val);
    }
    for (int m = tid; m < 288; m += 512) {
        float val = 0.f;
        if (m < MF) val = RATIO * (emx * S0p[bh * MPAD + m] + KEPS * 4096.0f);
        L[64 * 288 + m] = f2h_bits(val);
    }
    __syncthreads();
    short* dst = ctxw + (size_t)bh * (65 * 288);
    for (int idx = tid; idx < 65 * 36; idx += 512)
        *(short8*)(dst + idx * 8) = *(const short8*)&L[idx * 8];
}

// ---------------------------------------------------------------- q_pass ----
__global__ __launch_bounds__(512, 2)
void q_pass(const float* __restrict__ qin, const short* __restrict__ projw,
            const short* __restrict__ ctxw, float* __restrict__ outp)
{
    __shared__ __align__(16) short projL[MPAD * PSTR];
    __shared__ __align__(16) short ctxL[65 * QSTR];    // ctxT[e'][m] f16

    const int tid = threadIdx.x;
    const int bh = blockIdx.x >> 4, rt = blockIdx.x & 15;
    const int c = tid & 15, g = (tid >> 4) & 3, w = tid >> 6;

    // ---- stage pre-converted proj (f16, DNORM folded) + ctx
    for (int idx = tid; idx < MPAD * 8; idx += 512) {
        const int r = idx >> 3, s = idx & 7;
        *(short8*)&projL[r * PSTR + s * 8] = *(const short8*)(projw + (size_t)r * 64 + s * 8);
    }
    {
        const short* src = ctxw + (size_t)bh * (65 * 288);
        for (int idx = tid; idx < 65 * 36; idx += 512) {
            const int r = idx / 36, s = idx - r * 36;
            *(short8*)&ctxL[r * QSTR + s * 8] = *(const short8*)(src + r * 288 + s * 8);
        }
    }
    __syncthreads();   // proj + ctx ready

    for (int rg = 0; rg < 2; ++rg) {
        const int rowbase = rt * 256 + rg * 128;
        // ---- load q B-frags (row = rowbase + 16w + c), diag
        half8 bf0, bf1;
        float dsum = 0.f;
        {
            const float* qs = qin + ((size_t)bh * NTOK + rowbase + 16 * w + c) * DIM;
            #pragma unroll
            for (int ksi = 0; ksi < 2; ++ksi) {
                const float* p4 = qs + ksi * 32 + 8 * g;
                float4 x0 = *(const float4*)p4;
                float4 x1 = *(const float4*)(p4 + 4);
                dsum += x0.x*x0.x + x0.y*x0.y + x0.z*x0.z + x0.w*x0.w
                      + x1.x*x1.x + x1.y*x1.y + x1.z*x1.z + x1.w*x1.w;
                half8& bf = ksi ? bf1 : bf0;
                bf[0]=(_Float16)x0.x; bf[1]=(_Float16)x0.y; bf[2]=(_Float16)x0.z; bf[3]=(_Float16)x0.w;
                bf[4]=(_Float16)x1.x; bf[5]=(_Float16)x1.y; bf[6]=(_Float16)x1.z; bf[7]=(_Float16)x1.w;
            }
        }
        float t1 = dsum + __shfl_xor(dsum, 16);
        const float diagc = (t1 + __shfl_xor(t1, 32)) * DIAGC;   // diag of own row c

        // ---- GEMM1: dd^T = proj @ q^T : lane (c,g) holds dd[f=16t+4g+r2][row=c]
        floatx4 dd[17];
        #pragma unroll
        for (int t = 0; t < 17; ++t) {
            const short* ap = &projL[(16 * t + c) * PSTR + 8 * g];
            half8 a0 = *(const half8*)ap;
            half8 a1 = *(const half8*)(ap + 32);
            floatx4 d = {0.f, 0.f, 0.f, 0.f};
            d = __builtin_amdgcn_mfma_f32_16x16x32_f16(a0, bf0, d, 0, 0, 0);
            d = __builtin_amdgcn_mfma_f32_16x16x32_f16(a1, bf1, d, 0, 0, 0);
            dd[t] = d;
        }
        // ---- per-row max over valid f
        float mx = -3.0e38f;
        #pragma unroll
        for (int t = 0; t < 17; ++t) {
            #pragma unroll
            for (int r2 = 0; r2 < 4; ++r2) {
                const bool fval = (t < 16) || (4 * g + r2 < 10);
                if (fval) mx = fmaxf(mx, dd[t][r2]);
            }
        }
        mx = fmaxf(mx, __shfl_xor(mx, 16));
        mx = fmaxf(mx, __shfl_xor(mx, 32));

        // ---- qp in registers as 16x16x16 B-frags; denominator via VALU dot
        half4 bq[17];
        float denp = 0.f;
        #pragma unroll
        for (int t = 0; t < 17; ++t) {
            half4 b;
            #pragma unroll
            for (int r2 = 0; r2 < 4; ++r2) {
                float val = __expf(dd[t][r2] - diagc - mx) + KEPS;
                b[r2] = (_Float16)val;
                denp += val * h2f(ctxL[64 * QSTR + 16 * t + 4 * g + r2]);
            }
            bq[t] = b;
        }
        denp += __shfl_xor(denp, 16);
        denp += __shfl_xor(denp, 32);

        // ---- GEMM2: out^T[e'][r] = ctxT @ qp^T  (contract m, 17 K-steps of 16)
        floatx4 acc[4];
        #pragma unroll
        for (int i = 0; i < 4; ++i) { acc[i][0]=0.f; acc[i][1]=0.f; acc[i][2]=0.f; acc[i][3]=0.f; }
        #pragma unroll
        for (int e4 = 0; e4 < 4; ++e4) {
            #pragma unroll
            for (int t = 0; t < 17; ++t) {
                half4 a4 = *(const half4*)&ctxL[(16 * e4 + c) * QSTR + 16 * t + 4 * g];
                acc[e4] = __builtin_amdgcn_mfma_f32_16x16x16f16(a4, bq[t], acc[e4], 0, 0, 0);
            }
        }
        // ---- normalize + store: lane (c,g) holds out[row c][e' = 16e4+4g+r2]
        float den = (denp == 0.f) ? 1e-5f : denp;
        const float inv = 1.0f / den;
        float* ob = outp + ((size_t)bh * NTOK + rowbase + 16 * w + c) * DIM;
        #pragma unroll
        for (int e4 = 0; e4 < 4; ++e4) {
            float4 o = make_float4(acc[e4][0] * inv, acc[e4][1] * inv,
                                   acc[e4][2] * inv, acc[e4][3] * inv);
            *(float4*)(ob + 16 * e4 + 4 * g) = o;
        }
    }
}

extern "C" void kernel_launch(void* const* d_in, const int* in_sizes, int n_in,
                              void* d_out, int out_size, void* d_ws, size_t ws_size,
                              hipStream_t stream)
{
    const float* q    = (const float*)d_in[0];
    const float* k    = (const float*)d_in[1];
    const float* v    = (const float*)d_in[2];
    const float* proj = (const float*)d_in[3];
    float* out = (float*)d_out;
    float* ws  = (float*)d_ws;

    const size_t offS = (size_t)BH * NCH * MPAD * 64;   // A0p partials
    const size_t offG = offS + (size_t)BH * MPAD;       // S0p (atomic f32)
    const size_t offC = offG + 64;                      // gmax (encoded uint)
    const size_t offP = offC + (size_t)BH * 65 * 288 / 2;   // ctxw shorts -> float slots
    // projw: 272*64 shorts = 8704 float slots; total ~5.07M floats (~20.3 MB)

    float* A0p = ws;
    float* S0p = ws + offS;
    unsigned int* gmax = (unsigned int*)(ws + offG);
    short* ctxw = (short*)(ws + offC);
    short* projw = (short*)(ws + offP);

    // zero S0p + gmax (contiguous)
    (void)hipMemsetAsync(S0p, 0, ((size_t)BH * MPAD + 64) * sizeof(float), stream);
    hipLaunchKernelGGL(k_pass, dim3(BH * NCH * 2), dim3(512), 0, stream,
                       k, v, proj, A0p, S0p, gmax);
    hipLaunchKernelGGL(reduce_ctx, dim3(BH), dim3(512), 0, stream,
                       A0p, S0p, gmax, proj, ctxw, projw);
    hipLaunchKernelGGL(q_pass, dim3(BH * 16), dim3(512), 0, stream,
                       q, projw, ctxw, out);
}

// Round 7
// 132.450 us; speedup vs baseline: 2.4331x; 2.4331x over previous
//
#include <hip/hip_runtime.h>
#include <math.h>

// Performer FAVOR+ fast attention — round 7.
// B=4 H=16 N=4096 D=64 M=266.
// = round 6 k_pass/reduce_ctx (XCD h-pairing, proj pre-convert) +
//   round 5 q_pass structure (1 row-group/block, no spills) reading projw f16.
// Round 6 lesson: 2 row-groups/block fully unrolled -> dd[17] live x2 ->
// 128-VGPR cap -> 350 MB scratch spill traffic. Keep q_pass register-lean.

#define BH 64
#define NTOK 4096
#define DIM 64
#define MF 266
#define MPAD 272
#define NCH 4
#define CHROWS 1024
#define SUBS 16
#define RATIO 0.06131393394849658f   // 266^-0.5
#define DNORM 0.35355339059327373f   // 64^-0.25
#define DIAGC 0.0625f                // 0.5 * 64^-0.5
#define KEPS 1e-4f

#define PSTR 72     // LDS row stride in shorts (144 B)
#define QSTR 296    // q_pass ctx stride in shorts (592 B)

typedef _Float16 half8 __attribute__((ext_vector_type(8)));
typedef _Float16 half4 __attribute__((ext_vector_type(4)));
typedef __fp16 fp16x2 __attribute__((ext_vector_type(2)));   // cvt_pkrtz native type
typedef float floatx4 __attribute__((ext_vector_type(4)));
typedef short short8 __attribute__((ext_vector_type(8)));
typedef short short4s __attribute__((ext_vector_type(4)));

__device__ __forceinline__ short f2h_bits(float f) {
    union { _Float16 h; short s; } u; u.h = (_Float16)f; return u.s;
}
__device__ __forceinline__ float h2f(short s) {
    union { short s; _Float16 h; } u; u.s = s; return (float)u.h;
}
__device__ __forceinline__ unsigned cvt_pk_bf16(float lo, float hi) {
    unsigned r;
    asm("v_cvt_pk_bf16_f32 %0, %1, %2" : "=v"(r) : "v"(lo), "v"(hi));
    return r;
}
__device__ __forceinline__ unsigned encf(float f) {
    unsigned u = __float_as_uint(f);
    return (u & 0x80000000u) ? ~u : (u | 0x80000000u);
}
__device__ __forceinline__ float decf(unsigned u) {
    u = (u & 0x80000000u) ? (u & 0x7FFFFFFFu) : ~u;
    return __uint_as_float(u);
}

// ---------------------------------------------------------------- k_pass ----
__global__ __launch_bounds__(512, 4)
void k_pass(const float* __restrict__ kin, const float* __restrict__ vin,
            const float* __restrict__ proj, float* __restrict__ A0p,
            float* __restrict__ S0p, unsigned int* __restrict__ gmax)
{
    __shared__ __align__(16) short kL[2][64 * PSTR];    // k f16 [n][d]
    __shared__ __align__(16) short vT[2][64 * PSTR];    // v bf16 [e][n]
    __shared__ float diagL[2][64];
    __shared__ __align__(16) short epS[16][16 * PSTR];  // per (wave,it): ep bf16 [f][n]

    const int tid = threadIdx.x;
    const int l = tid & 63, w = tid >> 6;
    const int c = tid & 15, g = (tid >> 4) & 3;
    // h from the HIGH bit: blocks rest and rest+256 share a k/v chunk and map
    // to the same XCD (256 % 8 == 0) -> second reader hits L2.
    const int h    = blockIdx.x >> 8;
    const int rest = blockIdx.x & 255;
    const int bh   = rest >> 2;
    const int ch   = rest & 3;
    const int nT = (h == 1 && w == 0) ? 2 : 1;
    const int t0 = (h == 0) ? w : (8 + w);              // second tile (it=1) is 16

    // ---- proj B-frags in registers (only this wave's tiles)
    half8 pj0[2], pj1[2];
    #pragma unroll
    for (int it = 0; it < 2; ++it) {
        half8 z;
        #pragma unroll
        for (int j = 0; j < 8; ++j) z[j] = (_Float16)0.f;
        pj0[it] = z; pj1[it] = z;
        const int t = it ? 16 : t0;
        const int f = 16 * t + c;
        if (it < nT && f < MF) {
            const float* ps = proj + (size_t)f * 64 + 8 * g;
            float4 x0 = *(const float4*)ps;
            float4 x1 = *(const float4*)(ps + 4);
            float4 x2 = *(const float4*)(ps + 32);
            float4 x3 = *(const float4*)(ps + 36);
            half8 b0, b1;
            b0[0]=(_Float16)(DNORM*x0.x); b0[1]=(_Float16)(DNORM*x0.y);
            b0[2]=(_Float16)(DNORM*x0.z); b0[3]=(_Float16)(DNORM*x0.w);
            b0[4]=(_Float16)(DNORM*x1.x); b0[5]=(_Float16)(DNORM*x1.y);
            b0[6]=(_Float16)(DNORM*x1.z); b0[7]=(_Float16)(DNORM*x1.w);
            b1[0]=(_Float16)(DNORM*x2.x); b1[1]=(_Float16)(DNORM*x2.y);
            b1[2]=(_Float16)(DNORM*x2.z); b1[3]=(_Float16)(DNORM*x2.w);
            b1[4]=(_Float16)(DNORM*x3.x); b1[5]=(_Float16)(DNORM*x3.y);
            b1[6]=(_Float16)(DNORM*x3.z); b1[7]=(_Float16)(DNORM*x3.w);
            pj0[it] = b0; pj1[it] = b1;
        }
    }

    const float* kb = kin + ((size_t)bh * NTOK + (size_t)ch * CHROWS) * DIM;
    const float* vb = vin + ((size_t)bh * NTOK + (size_t)ch * CHROWS) * DIM;

    // staging assignments
    const int srow = 8 * w + (l >> 3);     // k: row, d-segment (l&7)*8
    const int sd0  = (l & 7) * 8;
    const int vrow = l;                    // v: row = lane, e-segment 8w..8w+7
    const int ve0  = 8 * w;

    floatx4 acc[2][4];
    #pragma unroll
    for (int it = 0; it < 2; ++it)
        #pragma unroll
        for (int et = 0; et < 4; ++et) {
            acc[it][et][0]=0.f; acc[it][et][1]=0.f; acc[it][et][2]=0.f; acc[it][et][3]=0.f;
        }
    float s0acc[2] = {0.f, 0.f};
    float dmax = -3.0e38f;

    float4 ka0, ka1, va0, va1;

    auto issue_loads = [&](int s) {
        const float* ks = kb + (size_t)(64 * s + srow) * DIM + sd0;
        ka0 = *(const float4*)ks;
        ka1 = *(const float4*)(ks + 4);
        const float* vs = vb + (size_t)(64 * s + vrow) * DIM + ve0;
        va0 = *(const float4*)vs;
        va1 = *(const float4*)(vs + 4);
    };

    auto stage_write = [&](int buf) {
        // k -> f16 row-major
        union { fp16x2 h2[4]; short8 s8; } uk;
        uk.h2[0] = __builtin_amdgcn_cvt_pkrtz(ka0.x, ka0.y);
        uk.h2[1] = __builtin_amdgcn_cvt_pkrtz(ka0.z, ka0.w);
        uk.h2[2] = __builtin_amdgcn_cvt_pkrtz(ka1.x, ka1.y);
        uk.h2[3] = __builtin_amdgcn_cvt_pkrtz(ka1.z, ka1.w);
        *(short8*)&kL[buf][srow * PSTR + sd0] = uk.s8;
        // diag partial + 8-lane reduce
        float ds2 = ka0.x*ka0.x + ka0.y*ka0.y + ka0.z*ka0.z + ka0.w*ka0.w
                  + ka1.x*ka1.x + ka1.y*ka1.y + ka1.z*ka1.z + ka1.w*ka1.w;
        ds2 += __shfl_xor(ds2, 1);
        ds2 += __shfl_xor(ds2, 2);
        ds2 += __shfl_xor(ds2, 4);
        if ((l & 7) == 0) diagL[buf][srow] = ds2 * DIAGC;
        // v -> bf16 transposed [e][n]
        unsigned pv0 = cvt_pk_bf16(va0.x, va0.y);
        unsigned pv1 = cvt_pk_bf16(va0.z, va0.w);
        unsigned pv2 = cvt_pk_bf16(va1.x, va1.y);
        unsigned pv3 = cvt_pk_bf16(va1.z, va1.w);
        vT[buf][(ve0 + 0) * PSTR + vrow] = (short)(pv0 & 0xFFFF);
        vT[buf][(ve0 + 1) * PSTR + vrow] = (short)(pv0 >> 16);
        vT[buf][(ve0 + 2) * PSTR + vrow] = (short)(pv1 & 0xFFFF);
        vT[buf][(ve0 + 3) * PSTR + vrow] = (short)(pv1 >> 16);
        vT[buf][(ve0 + 4) * PSTR + vrow] = (short)(pv2 & 0xFFFF);
        vT[buf][(ve0 + 5) * PSTR + vrow] = (short)(pv2 >> 16);
        vT[buf][(ve0 + 6) * PSTR + vrow] = (short)(pv3 & 0xFFFF);
        vT[buf][(ve0 + 7) * PSTR + vrow] = (short)(pv3 >> 16);
    };

    // prologue: stage sub 0
    issue_loads(0);
    stage_write(0);
    __syncthreads();

    for (int s = 0; s < SUBS; ++s) {
        const int cur = s & 1;
        const bool more = (s + 1 < SUBS);
        if (more) issue_loads(s + 1);   // HBM latency hides under compute below

        // ---- GEMM1: dd = k @ (DNORM proj)^T ; epilogue -> epS (wave-private)
        #pragma unroll
        for (int nt = 0; nt < 4; ++nt) {
            const half8 a0 = *(const half8*)&kL[cur][(16 * nt + c) * PSTR + 8 * g];
            const half8 a1 = *(const half8*)&kL[cur][(16 * nt + c) * PSTR + 8 * g + 32];
            const float4 dg4 = *(const float4*)&diagL[cur][16 * nt + 4 * g];
            const float dgr[4] = {dg4.x, dg4.y, dg4.z, dg4.w};
            #pragma unroll
            for (int it = 0; it < 2; ++it) {
                if (it < nT) {
                    floatx4 d = {0.f, 0.f, 0.f, 0.f};
                    d = __builtin_amdgcn_mfma_f32_16x16x32_f16(a0, pj0[it], d, 0, 0, 0);
                    d = __builtin_amdgcn_mfma_f32_16x16x32_f16(a1, pj1[it], d, 0, 0, 0);
                    const bool t16 = (it == 1);
                    float ev[4];
                    #pragma unroll
                    for (int r = 0; r < 4; ++r) {
                        const float ddv = d[r];
                        if (!t16 || c < 10) dmax = fmaxf(dmax, ddv);
                        float e = __expf(ddv - dgr[r]);
                        if (t16 && c == 15) e = 1.0f;   // "ones" feature -> Vs in A0 row 271
                        s0acc[it] += e;
                        ev[r] = e;
                    }
                    uint2 pk;
                    pk.x = cvt_pk_bf16(ev[0], ev[1]);
                    pk.y = cvt_pk_bf16(ev[2], ev[3]);
                    *(uint2*)&epS[2 * w + it][c * PSTR + 16 * nt + 4 * g] = pk;
                }
            }
        }

        // ---- GEMM2: A0[e][f] += v^T @ ep   (contract n, bf16 16x16x32)
        #pragma unroll
        for (int ntp = 0; ntp < 2; ++ntp) {
            const short8 bq0 = *(const short8*)&epS[2 * w][c * PSTR + 32 * ntp + 8 * g];
            short8 bq1;
            if (nT == 2) bq1 = *(const short8*)&epS[2 * w + 1][c * PSTR + 32 * ntp + 8 * g];
            #pragma unroll
            for (int et = 0; et < 4; ++et) {
                const short8 av = *(const short8*)&vT[cur][(16 * et + c) * PSTR + 32 * ntp + 8 * g];
                acc[0][et] = __builtin_amdgcn_mfma_f32_16x16x32_bf16(av, bq0, acc[0][et], 0, 0, 0);
                if (nT == 2)
                    acc[1][et] = __builtin_amdgcn_mfma_f32_16x16x32_bf16(av, bq1, acc[1][et], 0, 0, 0);
            }
        }

        if (more) {
            stage_write(cur ^ 1);
            __syncthreads();
        }
    }

    // ---- epilogue: A0 partials [m][e] (lane holds e=16et+4g..+3 contiguous)
    {
        float* dst = A0p + (size_t)(bh * NCH + ch) * (MPAD * 64);
        #pragma unroll
        for (int it = 0; it < 2; ++it) {
            if (it < nT) {
                const int t = it ? 16 : t0;
                #pragma unroll
                for (int et = 0; et < 4; ++et)
                    *(floatx4*)&dst[(size_t)(16 * t + c) * 64 + 16 * et + 4 * g] = acc[it][et];
            }
        }
    }
    // ---- S0 atomics
    #pragma unroll
    for (int it = 0; it < 2; ++it) {
        if (it < nT) {
            const int t = it ? 16 : t0;
            float s = s0acc[it];
            s += __shfl_xor(s, 16);
            s += __shfl_xor(s, 32);
            if (g == 0 && (t < 16 || c < 10))
                atomicAdd(&S0p[bh * MPAD + 16 * t + c], s);
        }
    }
    // ---- dmax
    #pragma unroll
    for (int sft = 1; sft <= 32; sft <<= 1) dmax = fmaxf(dmax, __shfl_xor(dmax, sft));
    if (l == 0) atomicMax(gmax + bh, encf(dmax));
}

// ------------------------------------------------------------ reduce_ctx ----
// ctxT_ws[bh][e'][m] f16, e'=0..63 context cols, e'=64 k_cumsum; m padded to 288.
// Blocks 0..16 also convert proj -> projw f16 (DNORM folded, rows >= 266 zero).
__global__ __launch_bounds__(512, 1)
void reduce_ctx(const float* __restrict__ A0p, const float* __restrict__ S0p,
                const unsigned int* __restrict__ gmax, const float* __restrict__ proj,
                short* __restrict__ ctxw, short* __restrict__ projw)
{
    __shared__ __align__(16) short L[65 * 288];
    const int bh = blockIdx.x, tid = threadIdx.x;
    if (bh < 17) {   // proj f16 conversion: rows 16*bh .. 16*bh+15
        #pragma unroll
        for (int rep = 0; rep < 2; ++rep) {
            const int idx = rep * 512 + tid;
            const int f = 16 * bh + (idx >> 6);
            const int d = idx & 63;
            const float val = (f < MF) ? proj[(size_t)f * 64 + d] * DNORM : 0.f;
            projw[(size_t)f * 64 + d] = f2h_bits(val);
        }
    }
    const float emx = __expf(-decf(gmax[bh]));
    const int e = tid & 63, mi = tid >> 6;
    const float* base = A0p + (size_t)bh * NCH * MPAD * 64;
    float vs = 0.f;
    #pragma unroll
    for (int c2 = 0; c2 < NCH; ++c2)
        vs += base[(size_t)c2 * MPAD * 64 + (size_t)271 * 64 + e];   // "ones" row = Vs
    const float vsr = vs * KEPS;
    for (int m = mi; m < 288; m += 8) {
        float val = 0.f;
        if (m < MF) {
            float s = 0.f;
            #pragma unroll
            for (int c2 = 0; c2 < NCH; ++c2)
                s += base[(size_t)c2 * MPAD * 64 + (size_t)m * 64 + e];
            val = RATIO * (emx * s + vsr);
        }
        L[e * 288 + m] = f2h_bits(val);
    }
    for (int m = tid; m < 288; m += 512) {
        float val = 0.f;
        if (m < MF) val = RATIO * (emx * S0p[bh * MPAD + m] + KEPS * 4096.0f);
        L[64 * 288 + m] = f2h_bits(val);
    }
    __syncthreads();
    short* dst = ctxw + (size_t)bh * (65 * 288);
    for (int idx = tid; idx < 65 * 36; idx += 512)
        *(short8*)(dst + idx * 8) = *(const short8*)&L[idx * 8];
}

// ---------------------------------------------------------------- q_pass ----
__global__ __launch_bounds__(512, 2)
void q_pass(const float* __restrict__ qin, const short* __restrict__ projw,
            const short* __restrict__ ctxw, float* __restrict__ outp)
{
    __shared__ __align__(16) short projL[MPAD * PSTR];
    __shared__ __align__(16) short ctxL[65 * QSTR];    // ctxT[e'][m] f16

    const int tid = threadIdx.x;
    const int bh = blockIdx.x >> 5, rt = blockIdx.x & 31;
    const int c = tid & 15, g = (tid >> 4) & 3, w = tid >> 6;

    // ---- stage pre-converted proj (f16, DNORM folded) + ctx
    for (int idx = tid; idx < MPAD * 8; idx += 512) {
        const int r = idx >> 3, s = idx & 7;
        *(short8*)&projL[r * PSTR + s * 8] = *(const short8*)(projw + (size_t)r * 64 + s * 8);
    }
    {
        const short* src = ctxw + (size_t)bh * (65 * 288);
        for (int idx = tid; idx < 65 * 36; idx += 512) {
            const int r = idx / 36, s = idx - r * 36;
            *(short8*)&ctxL[r * QSTR + s * 8] = *(const short8*)(src + r * 288 + s * 8);
        }
    }
    // ---- load q B-frags (row R0 = rt*128 + 16w + c), diag
    half8 bf0, bf1;
    float dsum = 0.f;
    {
        const float* qs = qin + ((size_t)bh * NTOK + rt * 128 + 16 * w + c) * DIM;
        #pragma unroll
        for (int ksi = 0; ksi < 2; ++ksi) {
            const float* p4 = qs + ksi * 32 + 8 * g;
            float4 x0 = *(const float4*)p4;
            float4 x1 = *(const float4*)(p4 + 4);
            dsum += x0.x*x0.x + x0.y*x0.y + x0.z*x0.z + x0.w*x0.w
                  + x1.x*x1.x + x1.y*x1.y + x1.z*x1.z + x1.w*x1.w;
            half8& bf = ksi ? bf1 : bf0;
            bf[0]=(_Float16)x0.x; bf[1]=(_Float16)x0.y; bf[2]=(_Float16)x0.z; bf[3]=(_Float16)x0.w;
            bf[4]=(_Float16)x1.x; bf[5]=(_Float16)x1.y; bf[6]=(_Float16)x1.z; bf[7]=(_Float16)x1.w;
        }
    }
    float t1 = dsum + __shfl_xor(dsum, 16);
    const float diagc = (t1 + __shfl_xor(t1, 32)) * DIAGC;   // diag of own row c

    __syncthreads();   // proj + ctx ready

    // ---- GEMM1: dd^T = proj @ q^T : lane (c,g) holds dd[f=16t+4g+r2][row=c]
    floatx4 dd[17];
    #pragma unroll
    for (int t = 0; t < 17; ++t) {
        const short* ap = &projL[(16 * t + c) * PSTR + 8 * g];
        half8 a0 = *(const half8*)ap;
        half8 a1 = *(const half8*)(ap + 32);
        floatx4 d = {0.f, 0.f, 0.f, 0.f};
        d = __builtin_amdgcn_mfma_f32_16x16x32_f16(a0, bf0, d, 0, 0, 0);
        d = __builtin_amdgcn_mfma_f32_16x16x32_f16(a1, bf1, d, 0, 0, 0);
        dd[t] = d;
    }
    // ---- per-row max over valid f
    float mx = -3.0e38f;
    #pragma unroll
    for (int t = 0; t < 17; ++t) {
        #pragma unroll
        for (int r2 = 0; r2 < 4; ++r2) {
            const bool fval = (t < 16) || (4 * g + r2 < 10);
            if (fval) mx = fmaxf(mx, dd[t][r2]);
        }
    }
    mx = fmaxf(mx, __shfl_xor(mx, 16));
    mx = fmaxf(mx, __shfl_xor(mx, 32));

    // ---- qp in registers as 16x16x16 B-frags; denominator via VALU dot
    half4 bq[17];
    float denp = 0.f;
    #pragma unroll
    for (int t = 0; t < 17; ++t) {
        half4 b;
        #pragma unroll
        for (int r2 = 0; r2 < 4; ++r2) {
            float val = __expf(dd[t][r2] - diagc - mx) + KEPS;
            b[r2] = (_Float16)val;
            denp += val * h2f(ctxL[64 * QSTR + 16 * t + 4 * g + r2]);
        }
        bq[t] = b;
    }
    denp += __shfl_xor(denp, 16);
    denp += __shfl_xor(denp, 32);

    // ---- GEMM2: out^T[e'][r] = ctxT @ qp^T  (contract m, 17 K-steps of 16)
    floatx4 acc[4];
    #pragma unroll
    for (int i = 0; i < 4; ++i) { acc[i][0]=0.f; acc[i][1]=0.f; acc[i][2]=0.f; acc[i][3]=0.f; }
    #pragma unroll
    for (int e4 = 0; e4 < 4; ++e4) {
        #pragma unroll
        for (int t = 0; t < 17; ++t) {
            half4 a4 = *(const half4*)&ctxL[(16 * e4 + c) * QSTR + 16 * t + 4 * g];
            acc[e4] = __builtin_amdgcn_mfma_f32_16x16x16f16(a4, bq[t], acc[e4], 0, 0, 0);
        }
    }
    // ---- normalize + store: lane (c,g) holds out[row c][e' = 16e4+4g+r2]
    float den = (denp == 0.f) ? 1e-5f : denp;
    const float inv = 1.0f / den;
    float* ob = outp + ((size_t)bh * NTOK + rt * 128 + 16 * w + c) * DIM;
    #pragma unroll
    for (int e4 = 0; e4 < 4; ++e4) {
        float4 o = make_float4(acc[e4][0] * inv, acc[e4][1] * inv,
                               acc[e4][2] * inv, acc[e4][3] * inv);
        *(float4*)(ob + 16 * e4 + 4 * g) = o;
    }
}

extern "C" void kernel_launch(void* const* d_in, const int* in_sizes, int n_in,
                              void* d_out, int out_size, void* d_ws, size_t ws_size,
                              hipStream_t stream)
{
    const float* q    = (const float*)d_in[0];
    const float* k    = (const float*)d_in[1];
    const float* v    = (const float*)d_in[2];
    const float* proj = (const float*)d_in[3];
    float* out = (float*)d_out;
    float* ws  = (float*)d_ws;

    const size_t offS = (size_t)BH * NCH * MPAD * 64;   // A0p partials
    const size_t offG = offS + (size_t)BH * MPAD;       // S0p (atomic f32)
    const size_t offC = offG + 64;                      // gmax (encoded uint)
    const size_t offP = offC + (size_t)BH * 65 * 288 / 2;   // ctxw shorts -> float slots
    // projw: 272*64 shorts = 8704 float slots

    float* A0p = ws;
    float* S0p = ws + offS;
    unsigned int* gmax = (unsigned int*)(ws + offG);
    short* ctxw = (short*)(ws + offC);
    short* projw = (short*)(ws + offP);

    // zero S0p + gmax (contiguous)
    (void)hipMemsetAsync(S0p, 0, ((size_t)BH * MPAD + 64) * sizeof(float), stream);
    hipLaunchKernelGGL(k_pass, dim3(BH * NCH * 2), dim3(512), 0, stream,
                       k, v, proj, A0p, S0p, gmax);
    hipLaunchKernelGGL(reduce_ctx, dim3(BH), dim3(512), 0, stream,
                       A0p, S0p, gmax, proj, ctxw, projw);
    hipLaunchKernelGGL(q_pass, dim3(BH * 32), dim3(512), 0, stream,
                       q, projw, ctxw, out);
}